// Round 5
// baseline (199.021 us; speedup 1.0000x reference)
//
#include <hip/hip_runtime.h>
#include <hip/hip_bf16.h>

// Problem dims (fixed by setup_inputs):
//   B=4, S=2048, H=1024, NH=16, D=64, M = B*S = 8192
#define S_LEN   2048
#define NHEADS  16
#define HDIM    64
#define HID     1024
#define BATCH   4
#define M_ROWS  (BATCH * S_LEN)   // 8192

#define BM 256
#define BN 128
#define BK 64

typedef __attribute__((ext_vector_type(8))) short short8;
typedef __attribute__((ext_vector_type(4))) float floatx4;

__device__ __forceinline__ unsigned short f2bf_rne(float x) {
  union { float f; unsigned u; } v; v.f = x;
  unsigned r = v.u + 0x7fffu + ((v.u >> 16) & 1u);
  return (unsigned short)(r >> 16);
}

__device__ __forceinline__ float bf2f(unsigned short u) {
  union { unsigned u; float f; } c; c.u = ((unsigned)u) << 16;
  return c.f;
}

__device__ __forceinline__ void glds16(const unsigned short* g, unsigned short* l) {
  __builtin_amdgcn_global_load_lds(
      (const __attribute__((address_space(1))) unsigned int*)g,
      (__attribute__((address_space(3))) unsigned int*)l, 16, 0, 0);
}

// ---------------- fp32 -> bf16 cast, all 4 tensors in one dispatch ----------
#define HS4 (M_ROWS * HID / 4)        // 2097152
#define W4  (HID * HID / 4)           // 262144
__global__ __launch_bounds__(256) void cast_all(
    const float* __restrict__ hs, const float* __restrict__ Wq,
    const float* __restrict__ Wk, const float* __restrict__ Wv,
    unsigned short* __restrict__ hsb, unsigned short* __restrict__ wqb,
    unsigned short* __restrict__ wkb, unsigned short* __restrict__ wvb) {
  int idx = blockIdx.x * 256 + threadIdx.x;
  const float* in;
  unsigned short* out;
  int off;
  if (idx < HS4) {
    in = hs; out = hsb; off = idx;
  } else {
    int r = idx - HS4;
    int seg = r >> 18;          // W4 = 2^18
    off = r & (W4 - 1);
    in  = (seg == 0) ? Wq  : (seg == 1) ? Wk  : Wv;
    out = (seg == 0) ? wqb : (seg == 1) ? wkb : wvb;
  }
  float4 v = ((const float4*)in)[off];
  ushort4 o;
  o.x = f2bf_rne(v.x);
  o.y = f2bf_rne(v.y);
  o.z = f2bf_rne(v.z);
  o.w = f2bf_rne(v.w);
  ((ushort4*)out)[off] = o;
}

// ---------------- QKV projection GEMM ----------------
// C[m,n] = bf16(sum_k A[m,k]*W[n,k] + bias[n]); A: MxK bf16, W: NxK bf16.
// 256x128 tile, BK=64, 512 threads = 8 waves (4 m x 2 n), each wave 64x64 via
// 4x4 MFMA 16x16x32 (2 K-substeps per BK). global_load_lds width-16 staging
// with XOR bank swizzle on the SOURCE side: LDS chunk (R, c^(R&7)) holds
// global chunk (R, c) -> ds_read_b128 phases cover all 8 bank groups.
__global__ __launch_bounds__(512) void qkv_gemm(
    const unsigned short* __restrict__ A,
    const unsigned short* __restrict__ W0, const unsigned short* __restrict__ W1,
    const unsigned short* __restrict__ W2,
    const float* __restrict__ b0, const float* __restrict__ b1,
    const float* __restrict__ b2,
    unsigned short* __restrict__ O0, unsigned short* __restrict__ O1,
    unsigned short* __restrict__ O2) {
  const int K = HID;
  const int N = HID;
  const int z = blockIdx.z;
  const unsigned short* __restrict__ W = (z == 0) ? W0 : (z == 1) ? W1 : W2;
  const float* __restrict__ bias = (z == 0) ? b0 : (z == 1) ? b1 : b2;
  unsigned short* __restrict__ O = (z == 0) ? O0 : (z == 1) ? O1 : O2;

  __shared__ __align__(16) unsigned short As[BM * BK];  // 32 KB
  __shared__ __align__(16) unsigned short Bs[BN * BK];  // 16 KB

  const int tid = threadIdx.x;
  const int w = tid >> 6;          // 0..7
  const int lane = tid & 63;
  const int m0 = blockIdx.x * BM;
  const int n0 = blockIdx.y * BN;

  // staging: A = 32 segments of 1 KB (8 rows x 8 chunks of 16 B), B = 16.
  // Wave w owns A segments w*4+u (u=0..3) and B segments w*2+u (u=0..1).
  // Lane l -> local row lr=l>>3, LDS chunk l&7, global chunk (l&7)^lr.
  const int lr = lane >> 3;
  const int cc = (lane & 7) ^ lr;
  const unsigned short* gA[4];
  const unsigned short* gB[2];
  unsigned short* lA[4];
  unsigned short* lB[2];
  #pragma unroll
  for (int u = 0; u < 4; ++u) {
    const int seg = w * 4 + u;
    const int r = seg * 8 + lr;
    gA[u] = A + (size_t)(m0 + r) * K + cc * 8;
    lA[u] = As + seg * 512;
  }
  #pragma unroll
  for (int u = 0; u < 2; ++u) {
    const int seg = w * 2 + u;
    const int r = seg * 8 + lr;
    gB[u] = W + (size_t)(n0 + r) * K + cc * 8;
    lB[u] = Bs + seg * 512;
  }

  const int lrow = lane & 15;
  const int qd = lane >> 4;               // 0..3
  const int sw = lrow & 7;                // read-side swizzle key (row&7)
  const int arow = (w & 3) * 64 + lrow;   // wave m-offset
  const int brow = (w >> 2) * 64 + lrow;  // wave n-offset

  floatx4 acc[4][4] = {};

  for (int k0 = 0; k0 < K; k0 += BK) {
    #pragma unroll
    for (int u = 0; u < 4; ++u) glds16(gA[u] + k0, lA[u]);
    #pragma unroll
    for (int u = 0; u < 2; ++u) glds16(gB[u] + k0, lB[u]);
    __syncthreads();

    #pragma unroll
    for (int kk = 0; kk < 2; ++kk) {
      const int cp = (((kk << 2) | qd) ^ sw) * 8;  // swizzled chunk -> shorts
      short8 af[4], bf[4];
      #pragma unroll
      for (int im = 0; im < 4; ++im)
        af[im] = *(const short8*)(As + (arow + im * 16) * BK + cp);
      #pragma unroll
      for (int in = 0; in < 4; ++in)
        bf[in] = *(const short8*)(Bs + (brow + in * 16) * BK + cp);

      #pragma unroll
      for (int im = 0; im < 4; ++im)
        #pragma unroll
        for (int in = 0; in < 4; ++in)
          acc[im][in] = __builtin_amdgcn_mfma_f32_16x16x32_bf16(af[im], bf[in], acc[im][in], 0, 0, 0);
    }
    __syncthreads();
  }

  // epilogue: C/D layout col = lane&15, row = quad*4 + r; write bf16
  #pragma unroll
  for (int im = 0; im < 4; ++im) {
    #pragma unroll
    for (int in = 0; in < 4; ++in) {
      const int col = n0 + (w >> 2) * 64 + in * 16 + lrow;
      const float bb = bias[col];
      #pragma unroll
      for (int r = 0; r < 4; ++r) {
        const int row = m0 + (w & 3) * 64 + im * 16 + (qd << 2) + r;
        O[(size_t)row * N + col] = f2bf_rne(acc[im][in][r] + bb);
      }
    }
  }
}

// ---------------- log-sparse attention ----------------
// 8 lanes per query (lane = 8 dims, 16 B bf16 loads), 32 queries per block.
// Two-phase register budget: phase 1 prefetches K+Q+mask only (~60 VGPR),
// computes scores + softmax; phase 2 batch-loads the 12 V rows and
// accumulates. Lower peak VGPR -> more resident waves -> gather overlap.
__global__ __launch_bounds__(256) void logsparse_attn(
    const unsigned short* __restrict__ Q, const unsigned short* __restrict__ K,
    const unsigned short* __restrict__ V, const float* __restrict__ mask,
    float* __restrict__ out) {
  const int tid = threadIdx.x;
  const int l = tid & 7;
  const int qglob = blockIdx.x * 32 + (tid >> 3);

  const int i = qglob & (S_LEN - 1);
  const int h = (qglob >> 11) & (NHEADS - 1);
  const int b = qglob >> 15;

  const size_t base = (size_t)b * S_LEN * HID + h * HDIM + l * 8;

  int js[12];
  js[0] = i;
  int nj = 1;
  for (int d = 1; d <= i; d <<= 1) js[nj++] = i - d;
  #pragma unroll
  for (int t = 0; t < 12; ++t)
    if (t >= nj) js[t] = i;   // clamp: valid row, zeroed after mask

  // ---- phase 1: K + Q + mask prefetch, scores, softmax ----
  short8 k8[12];
  #pragma unroll
  for (int t = 0; t < 12; ++t)
    k8[t] = *(const short8*)(K + base + (size_t)js[t] * HID);
  const short8 q8 = *(const short8*)(Q + base + (size_t)i * HID);
  float mk[12];
  #pragma unroll
  for (int t = 0; t < 12; ++t)
    mk[t] = mask[b * S_LEN + js[t]];

  float qf[8];
  #pragma unroll
  for (int e = 0; e < 8; ++e) qf[e] = bf2f((unsigned short)q8[e]);

  float s[12];
  #pragma unroll
  for (int t = 0; t < 12; ++t) {
    float p = 0.f;
    #pragma unroll
    for (int e = 0; e < 8; ++e) p += qf[e] * bf2f((unsigned short)k8[t][e]);
    p += __shfl_xor(p, 1, 64);
    p += __shfl_xor(p, 2, 64);
    p += __shfl_xor(p, 4, 64);
    s[t] = (t < nj) ? (p * 0.125f + mk[t]) : -1e30f;
  }

  float mx = s[0];
  #pragma unroll
  for (int t = 1; t < 12; ++t) mx = fmaxf(mx, s[t]);
  float lsum = 0.f;
  #pragma unroll
  for (int t = 0; t < 12; ++t) { s[t] = __expf(s[t] - mx); lsum += s[t]; }
  const float inv = 1.f / lsum;

  // ---- phase 2: V batch load + accumulate ----
  short8 v8[12];
  #pragma unroll
  for (int t = 0; t < 12; ++t)
    v8[t] = *(const short8*)(V + base + (size_t)js[t] * HID);

  float o[8] = {};
  #pragma unroll
  for (int t = 0; t < 12; ++t) {
    #pragma unroll
    for (int e = 0; e < 8; ++e) o[e] += s[t] * bf2f((unsigned short)v8[t][e]);
  }

  float* op = out + base + (size_t)i * HID;
  float4 o0 = {o[0] * inv, o[1] * inv, o[2] * inv, o[3] * inv};
  float4 o1 = {o[4] * inv, o[5] * inv, o[6] * inv, o[7] * inv};
  *(float4*)(op) = o0;
  *(float4*)(op + 4) = o1;
}

// ---------------- launch ----------------
extern "C" void kernel_launch(void* const* d_in, const int* in_sizes, int n_in,
                              void* d_out, int out_size, void* d_ws, size_t ws_size,
                              hipStream_t stream) {
  const float* hs   = (const float*)d_in[0];
  const float* mask = (const float*)d_in[1];
  const float* Wq   = (const float*)d_in[2];
  const float* bq   = (const float*)d_in[3];
  const float* Wk   = (const float*)d_in[4];
  const float* bk   = (const float*)d_in[5];
  const float* Wv   = (const float*)d_in[6];
  const float* bv   = (const float*)d_in[7];
  float* out = (float*)d_out;

  // workspace layout (all bf16)
  unsigned short* hsb = (unsigned short*)d_ws;                  // M*H
  unsigned short* wqb = hsb + (size_t)M_ROWS * HID;             // H*H
  unsigned short* wkb = wqb + (size_t)HID * HID;
  unsigned short* wvb = wkb + (size_t)HID * HID;
  unsigned short* Qb = wvb + (size_t)HID * HID;                 // M*H
  unsigned short* Kb = Qb + (size_t)M_ROWS * HID;
  unsigned short* Vb = Kb + (size_t)M_ROWS * HID;

  // casts: one dispatch for hs + Wq + Wk + Wv
  {
    int quads = HS4 + 3 * W4;                 // 2883584
    cast_all<<<quads / 256, 256, 0, stream>>>(hs, Wq, Wk, Wv, hsb, wqb, wkb, wvb);
  }

  // QKV projections
  {
    dim3 grid(M_ROWS / BM, HID / BN, 3);     // 32 x 8 x 3
    qkv_gemm<<<grid, 512, 0, stream>>>(hsb, wqb, wkb, wvb, bq, bk, bv, Qb, Kb, Vb);
  }

  // sparse attention: 32 queries per 256-thread block
  {
    int blocks = (BATCH * NHEADS * S_LEN) / 32;   // 4096
    logsparse_attn<<<blocks, 256, 0, stream>>>(Qb, Kb, Vb, mask, out);
  }
}

// Round 7
// 180.415 us; speedup vs baseline: 1.1031x; 1.1031x over previous
//
#include <hip/hip_runtime.h>
#include <hip/hip_bf16.h>

// Problem dims (fixed by setup_inputs):
//   B=4, S=2048, H=1024, NH=16, D=64, M = B*S = 8192
#define S_LEN   2048
#define NHEADS  16
#define HDIM    64
#define HID     1024
#define BATCH   4
#define M_ROWS  (BATCH * S_LEN)   // 8192

#define BM 128
#define BN 128
#define BK 64

typedef __attribute__((ext_vector_type(8))) short short8;
typedef __attribute__((ext_vector_type(4))) float floatx4;   // clang vector (NT-builtin OK)
typedef __attribute__((ext_vector_type(4))) unsigned short ushort4v;

__device__ __forceinline__ unsigned short f2bf_rne(float x) {
  union { float f; unsigned u; } v; v.f = x;
  unsigned r = v.u + 0x7fffu + ((v.u >> 16) & 1u);
  return (unsigned short)(r >> 16);
}

__device__ __forceinline__ float bf2f(unsigned short u) {
  union { unsigned u; float f; } c; c.u = ((unsigned)u) << 16;
  return c.f;
}

__device__ __forceinline__ void glds16(const unsigned short* g, unsigned short* l) {
  __builtin_amdgcn_global_load_lds(
      (const __attribute__((address_space(1))) unsigned int*)g,
      (__attribute__((address_space(3))) unsigned int*)l, 16, 0, 0);
}

// ---------------- fp32 -> bf16 cast, all 4 tensors in one dispatch ----------
#define HS4 (M_ROWS * HID / 4)        // 2097152
#define W4  (HID * HID / 4)           // 262144
__global__ __launch_bounds__(256) void cast_all(
    const float* __restrict__ hs, const float* __restrict__ Wq,
    const float* __restrict__ Wk, const float* __restrict__ Wv,
    unsigned short* __restrict__ hsb, unsigned short* __restrict__ wqb,
    unsigned short* __restrict__ wkb, unsigned short* __restrict__ wvb) {
  int idx = blockIdx.x * 256 + threadIdx.x;
  const float* in;
  unsigned short* out;
  int off;
  if (idx < HS4) {
    in = hs; out = hsb; off = idx;
  } else {
    int r = idx - HS4;
    int seg = r >> 18;          // W4 = 2^18
    off = r & (W4 - 1);
    in  = (seg == 0) ? Wq  : (seg == 1) ? Wk  : Wv;
    out = (seg == 0) ? wqb : (seg == 1) ? wkb : wvb;
  }
  // fp32 inputs are read exactly once -> non-temporal (don't pollute L2)
  floatx4 v = __builtin_nontemporal_load((const floatx4*)in + off);
  ushort4v o;
  o.x = f2bf_rne(v.x);
  o.y = f2bf_rne(v.y);
  o.z = f2bf_rne(v.z);
  o.w = f2bf_rne(v.w);
  ((ushort4v*)out)[off] = o;
}

// ---------------- QKV projection GEMM (R4 config: best measured) -----------
// C[m,n] = bf16(sum_k A[m,k]*W[n,k] + bias[n]); A: MxK bf16, W: NxK bf16.
// 128x128 tile, BK=64, 4 waves (2x2), each wave 64x64 via 4x4 MFMA 16x16x32
// (2 K-substeps per BK). global_load_lds width-16 staging with XOR bank
// swizzle on the SOURCE side: LDS chunk (R, c^(R&7)) holds global chunk
// (R, c) -> ds_read_b128 phases cover all 8 bank groups (conflicts = 0).
__global__ __launch_bounds__(256) void qkv_gemm(
    const unsigned short* __restrict__ A,
    const unsigned short* __restrict__ W0, const unsigned short* __restrict__ W1,
    const unsigned short* __restrict__ W2,
    const float* __restrict__ b0, const float* __restrict__ b1,
    const float* __restrict__ b2,
    unsigned short* __restrict__ O0, unsigned short* __restrict__ O1,
    unsigned short* __restrict__ O2) {
  const int K = HID;
  const int N = HID;
  const int z = blockIdx.z;
  const unsigned short* __restrict__ W = (z == 0) ? W0 : (z == 1) ? W1 : W2;
  const float* __restrict__ bias = (z == 0) ? b0 : (z == 1) ? b1 : b2;
  unsigned short* __restrict__ O = (z == 0) ? O0 : (z == 1) ? O1 : O2;

  __shared__ __align__(16) unsigned short As[BM * BK];  // 16 KB
  __shared__ __align__(16) unsigned short Bs[BN * BK];  // 16 KB

  const int tid = threadIdx.x;
  const int w = tid >> 6;
  const int lane = tid & 63;
  const int m0 = blockIdx.x * BM;
  const int n0 = blockIdx.y * BN;

  // staging: 16 segments of 1 KB, each = 8 rows x 8 chunks(16B). Wave w owns
  // segments w*4+u (u=0..3). Lane l -> local row lr=l>>3, LDS chunk l&7,
  // global chunk (l&7)^lr (XOR swizzle).
  const int lr = lane >> 3;
  const int cc = (lane & 7) ^ lr;
  const unsigned short* gA[4];
  const unsigned short* gB[4];
  unsigned short* lA[4];
  unsigned short* lB[4];
  #pragma unroll
  for (int u = 0; u < 4; ++u) {
    const int seg = w * 4 + u;
    const int r = seg * 8 + lr;
    gA[u] = A + (size_t)(m0 + r) * K + cc * 8;
    gB[u] = W + (size_t)(n0 + r) * K + cc * 8;
    lA[u] = As + seg * 512;
    lB[u] = Bs + seg * 512;
  }

  const int lrow = lane & 15;
  const int qd = lane >> 4;              // 0..3
  const int sw = lrow & 7;               // read-side swizzle key (row&7)
  const int arow = (w & 1) * 64 + lrow;  // wave m-offset
  const int brow = (w >> 1) * 64 + lrow; // wave n-offset

  floatx4 acc[4][4] = {};

  for (int k0 = 0; k0 < K; k0 += BK) {
    #pragma unroll
    for (int u = 0; u < 4; ++u) {
      glds16(gA[u] + k0, lA[u]);
      glds16(gB[u] + k0, lB[u]);
    }
    __syncthreads();

    #pragma unroll
    for (int kk = 0; kk < 2; ++kk) {
      const int cp = (((kk << 2) | qd) ^ sw) * 8;  // swizzled chunk -> shorts
      short8 af[4], bf[4];
      #pragma unroll
      for (int im = 0; im < 4; ++im)
        af[im] = *(const short8*)(As + (arow + im * 16) * BK + cp);
      #pragma unroll
      for (int in = 0; in < 4; ++in)
        bf[in] = *(const short8*)(Bs + (brow + in * 16) * BK + cp);

      #pragma unroll
      for (int im = 0; im < 4; ++im)
        #pragma unroll
        for (int in = 0; in < 4; ++in)
          acc[im][in] = __builtin_amdgcn_mfma_f32_16x16x32_bf16(af[im], bf[in], acc[im][in], 0, 0, 0);
    }
    __syncthreads();
  }

  // epilogue: C/D layout col = lane&15, row = quad*4 + r; write bf16
  #pragma unroll
  for (int im = 0; im < 4; ++im) {
    #pragma unroll
    for (int in = 0; in < 4; ++in) {
      const int col = n0 + (w >> 1) * 64 + in * 16 + lrow;
      const float bb = bias[col];
      #pragma unroll
      for (int r = 0; r < 4; ++r) {
        const int row = m0 + (w & 1) * 64 + im * 16 + (qd << 2) + r;
        O[(size_t)row * N + col] = f2bf_rne(acc[im][in][r] + bb);
      }
    }
  }
}

// ---------------- log-sparse attention ----------------
// 8 lanes per query (lane = 8 dims, 16 B bf16 loads), 32 queries per block.
// Two-phase register budget (K+scores+softmax, then V+accumulate).
// XCD-contiguous block swizzle: blocks for one head stay on one XCD's L2.
// Non-temporal output stores: out (32 MB, never re-read) must not evict the
// K/V gather working set from L2.
__global__ __launch_bounds__(256) void logsparse_attn(
    const unsigned short* __restrict__ Q, const unsigned short* __restrict__ K,
    const unsigned short* __restrict__ V, const float* __restrict__ mask,
    float* __restrict__ out) {
  // 4096 blocks -> XCD x gets contiguous logical range [x*512, (x+1)*512)
  const int bid = (blockIdx.x & 7) * 512 + (blockIdx.x >> 3);
  const int tid = threadIdx.x;
  const int l = tid & 7;
  const int qglob = bid * 32 + (tid >> 3);

  const int i = qglob & (S_LEN - 1);
  const int h = (qglob >> 11) & (NHEADS - 1);
  const int b = qglob >> 15;

  const size_t base = (size_t)b * S_LEN * HID + h * HDIM + l * 8;

  int js[12];
  js[0] = i;
  int nj = 1;
  for (int d = 1; d <= i; d <<= 1) js[nj++] = i - d;
  #pragma unroll
  for (int t = 0; t < 12; ++t)
    if (t >= nj) js[t] = i;   // clamp: valid row, zeroed after mask

  // ---- phase 1: K + Q + mask prefetch, scores, softmax ----
  short8 k8[12];
  #pragma unroll
  for (int t = 0; t < 12; ++t)
    k8[t] = *(const short8*)(K + base + (size_t)js[t] * HID);
  const short8 q8 = *(const short8*)(Q + base + (size_t)i * HID);
  float mk[12];
  #pragma unroll
  for (int t = 0; t < 12; ++t)
    mk[t] = mask[b * S_LEN + js[t]];

  float qf[8];
  #pragma unroll
  for (int e = 0; e < 8; ++e) qf[e] = bf2f((unsigned short)q8[e]);

  float s[12];
  #pragma unroll
  for (int t = 0; t < 12; ++t) {
    float p = 0.f;
    #pragma unroll
    for (int e = 0; e < 8; ++e) p += qf[e] * bf2f((unsigned short)k8[t][e]);
    p += __shfl_xor(p, 1, 64);
    p += __shfl_xor(p, 2, 64);
    p += __shfl_xor(p, 4, 64);
    s[t] = (t < nj) ? (p * 0.125f + mk[t]) : -1e30f;
  }

  float mx = s[0];
  #pragma unroll
  for (int t = 1; t < 12; ++t) mx = fmaxf(mx, s[t]);
  float lsum = 0.f;
  #pragma unroll
  for (int t = 0; t < 12; ++t) { s[t] = __expf(s[t] - mx); lsum += s[t]; }
  const float inv = 1.f / lsum;

  // ---- phase 2: V batch load + accumulate ----
  short8 v8[12];
  #pragma unroll
  for (int t = 0; t < 12; ++t)
    v8[t] = *(const short8*)(V + base + (size_t)js[t] * HID);

  float o[8] = {};
  #pragma unroll
  for (int t = 0; t < 12; ++t) {
    #pragma unroll
    for (int e = 0; e < 8; ++e) o[e] += s[t] * bf2f((unsigned short)v8[t][e]);
  }

  float* op = out + base + (size_t)i * HID;
  floatx4 o0 = {o[0] * inv, o[1] * inv, o[2] * inv, o[3] * inv};
  floatx4 o1 = {o[4] * inv, o[5] * inv, o[6] * inv, o[7] * inv};
  __builtin_nontemporal_store(o0, (floatx4*)op);
  __builtin_nontemporal_store(o1, (floatx4*)(op + 4));
}

// ---------------- launch ----------------
extern "C" void kernel_launch(void* const* d_in, const int* in_sizes, int n_in,
                              void* d_out, int out_size, void* d_ws, size_t ws_size,
                              hipStream_t stream) {
  const float* hs   = (const float*)d_in[0];
  const float* mask = (const float*)d_in[1];
  const float* Wq   = (const float*)d_in[2];
  const float* bq   = (const float*)d_in[3];
  const float* Wk   = (const float*)d_in[4];
  const float* bk   = (const float*)d_in[5];
  const float* Wv   = (const float*)d_in[6];
  const float* bv   = (const float*)d_in[7];
  float* out = (float*)d_out;

  // workspace layout (all bf16)
  unsigned short* hsb = (unsigned short*)d_ws;                  // M*H
  unsigned short* wqb = hsb + (size_t)M_ROWS * HID;             // H*H
  unsigned short* wkb = wqb + (size_t)HID * HID;
  unsigned short* wvb = wkb + (size_t)HID * HID;
  unsigned short* Qb = wvb + (size_t)HID * HID;                 // M*H
  unsigned short* Kb = Qb + (size_t)M_ROWS * HID;
  unsigned short* Vb = Kb + (size_t)M_ROWS * HID;

  // casts: one dispatch for hs + Wq + Wk + Wv
  {
    int quads = HS4 + 3 * W4;                 // 2883584
    cast_all<<<quads / 256, 256, 0, stream>>>(hs, Wq, Wk, Wv, hsb, wqb, wkb, wvb);
  }

  // QKV projections
  {
    dim3 grid(M_ROWS / BM, HID / BN, 3);     // 64 x 8 x 3
    qkv_gemm<<<grid, 256, 0, stream>>>(hsb, wqb, wkb, wvb, bq, bk, bv, Qb, Kb, Vb);
  }

  // sparse attention: 32 queries per 256-thread block
  {
    int blocks = (BATCH * NHEADS * S_LEN) / 32;   // 4096
    logsparse_attn<<<blocks, 256, 0, stream>>>(Qb, Kb, Vb, mask, out);
  }
}